// Round 6
// baseline (374.214 us; speedup 1.0000x reference)
//
#include <hip/hip_runtime.h>

typedef unsigned short u16;
typedef __attribute__((ext_vector_type(8)))  short          short8;
typedef __attribute__((ext_vector_type(8)))  unsigned short ushort8v;
typedef __attribute__((ext_vector_type(4)))  unsigned short ushort4v;
typedef __attribute__((ext_vector_type(16))) float          float16v;

__device__ __forceinline__ float bf2f(u16 u){
  union { unsigned int i; float f; } x; x.i = ((unsigned int)u) << 16; return x.f;
}
// scalar fallback (node-0 broadcast only) — RNE, identical to v_cvt_pk_bf16_f32
__device__ __forceinline__ u16 f2bf(float f){
  union { float f; unsigned int i; } x; x.f = f;
  unsigned int u = x.i;
  unsigned int r = (u + 0x7FFFu + ((u >> 16) & 1u)) >> 16;
  return (u16)r;
}
// HW packed f32x2 -> bf16x2 (RNE), 1 VALU op for 2 elements.
__device__ __forceinline__ unsigned int cvtpk_bf16(float lo, float hi){
  unsigned int r;
  asm("v_cvt_pk_bf16_f32 %0, %1, %2" : "=v"(r) : "v"(lo), "v"(hi));
  return r;
}
// leaky-relu, branchless
__device__ __forceinline__ float lk(float v){ return fmaxf(v, 0.01f*v); }

// ------- weight permute+quantize into MFMA-fragment-TILED layout -------------
// Tile = (32 out-rows) x (one k-step of 16): 512 bf16 = 1 KB, stored as
// lane-major fragments: elem[(tile*64 + lane)*8 + e], where lane l holds
// A[row = rb*32 + (l&31)][k = jk*16 + (l>>5)*8 + e].  A-loads in the k-loop
// become ONE fully-coalesced 1 KB burst per instruction.
// ws layout (bf16): L1 @0 (8 rb x 24 jk tiles), L2 @98304 (4 x 48), L3 @196608 (2 x 24)
// Single copy (432 KB, L2-resident). Probes that FAILED: 8x replication
// (capacity regression), k-phase rotation (scratch spill), 512-thr occupancy
// (null), 2-tree A-share at 1 blk/CU (lost phase overlap, +20us).
__global__ void permute_w(const float* __restrict__ W1, const float* __restrict__ W2,
                          const float* __restrict__ W3, u16* __restrict__ ws){
  int t = blockIdx.x*256 + threadIdx.x;
  const float* src; u16* dst; int C, local;
  if (t < 98304)       { src = W1; dst = ws;          C = 128; local = t; }
  else if (t < 196608) { src = W2; dst = ws + 98304;  C = 256; local = t - 98304; }
  else if (t < 221184) { src = W3; dst = ws + 196608; C = 128; local = t - 196608; }
  else return;
  const int NJK  = 3*C/16;
  const int tile = local >> 9, within = local & 511;
  const int lane = within >> 3, e = within & 7;
  const int rb = tile / NJK, jk = tile - rb*NJK;
  const int o  = rb*32 + (lane & 31);
  const int kg = jk*16 + (lane >> 5)*8 + e;
  const int j  = kg / C, c = kg - j*C;
  dst[local] = f2bf(src[o*3*C + c*3 + j]);
}

// ---------------- fused per-tree layer (4 waves, in-register output) ----------
// GEMM out[O x 127] = W[O x 3C] * G, where G[j*C+c][m] = bIn[idx[3m+j]][c]
// PAIR = A-tiles (32 rows each) per wave; each random-node B-gather feeds
// PAIR MFMAs. PAIR raised 2->4 for L1/L2 to HALVE the ds_read_b128 gather
// count (random node indices make gathers ~2x bank-conflicted and layout
// cannot fix randomness -- fewer gathers is the only lever). The repeated
// A-streams are wave-lockstep within the block -> L1 vector cache absorbs
// the re-reads; W stays L2-resident.
// Wave w: u0 = w*NTL; rbg = u0>>2 (PAIR-tile row group), nt0 = u0&3.
// Output stays in acc until after the stats __syncthreads (fences k-loop LDS
// reads), THEN is written to bOut/bOutF — which may ALIAS bIn.
template<int CIN, int O, int SIN, int OST, int NTL, int PAIR, bool LEAKY, bool IS_L3>
__device__ __forceinline__ void do_layer(const u16* __restrict__ Wt,
                                         const float* __restrict__ bias,
                                         const u16* bIn, u16* bOut, float* bOutF,
                                         const int* sidx, float* sstat,
                                         int tid, float* out_mean, float* out_inv)
{
  constexpr int KS  = CIN/16;     // k-steps per j segment
  constexpr int NJK = 3*KS;       // total k-steps
  static_assert((O/(32*PAIR))*4 == 4*NTL, "work split mismatch");
  const int w = tid >> 6, lane = tid & 63, l31 = lane & 31, h = lane >> 5;

  const int u0  = w*NTL;
  const int rbg = u0 >> 2;        // PAIR-tile row-group id
  const int nt0 = u0 & 3;         // first n-tile
  const int r0  = rbg * 32 * PAIR;

  // tiled A bases: tile index = (rbg*PAIR + p)*NJK + jk, lane-major inside
  const u16* aP[PAIR];
#pragma unroll
  for (int p = 0; p < PAIR; ++p)
    aP[p] = Wt + ((size_t)(rbg*PAIR + p)*NJK)*512 + lane*8;

  int boff[NTL][3];
#pragma unroll
  for (int n = 0; n < NTL; ++n){
    int m = (nt0 + n)*32 + l31;   // position 0..127 (127 is pad, masked below)
#pragma unroll
    for (int j = 0; j < 3; ++j){
      int i = sidx[3*m + j];      // m==127 hits zero-padded sidx[381..383]
      boff[n][j] = i*SIN + h*8;
    }
  }

  float16v acc[NTL][PAIR];
#pragma unroll
  for (int n = 0; n < NTL; ++n)
#pragma unroll
    for (int p = 0; p < PAIR; ++p) acc[n][p] = {};

#pragma unroll
  for (int jk = 0; jk < NJK; ++jk){
    const int j    = jk / KS;
    const int coff = (jk - j*KS)*16;
    short8 A[PAIR];
#pragma unroll
    for (int p = 0; p < PAIR; ++p) A[p] = *(const short8*)(aP[p] + jk*512);
#pragma unroll
    for (int n = 0; n < NTL; ++n){
      short8 Bf = *(const short8*)(bIn + boff[n][j] + coff);
#pragma unroll
      for (int p = 0; p < PAIR; ++p)
        acc[n][p] = __builtin_amdgcn_mfma_f32_32x32x16_bf16(A[p], Bf, acc[n][p], 0, 0, 0);
    }
  }

  // post-loop: bias add (L2-hot, off the k-loop critical path) + stats partials
  float s = 0.f, s2 = 0.f;
#pragma unroll
  for (int n = 0; n < NTL; ++n){
    const int m = (nt0 + n)*32 + l31;
    const bool valid = (m <= 126);
#pragma unroll
    for (int p = 0; p < PAIR; ++p)
#pragma unroll
      for (int g = 0; g < 4; ++g){
        const int rowb = r0 + p*32 + 8*g + 4*h;   // C/D row = (reg&3)+8*(reg>>2)+4h
#pragma unroll
        for (int q = 0; q < 4; ++q){
          float raw = acc[n][p][4*g + q] + bias[rowb + q];
          acc[n][p][4*g + q] = raw;
          if (valid){ s += raw; s2 += raw*raw; }
        }
      }
  }

  // block-wide stats; this __syncthreads also FENCES all k-loop reads of bIn,
  // making it safe for the store phase below to overwrite bIn's region.
#pragma unroll
  for (int off = 32; off >= 1; off >>= 1){
    s  += __shfl_down(s,  off, 64);
    s2 += __shfl_down(s2, off, 64);
  }
  if (lane == 0){ sstat[w*2] = s; sstat[w*2+1] = s2; }
  __syncthreads();

  const float tot  = sstat[0] + sstat[2] + sstat[4] + sstat[6];
  const float tot2 = sstat[1] + sstat[3] + sstat[5] + sstat[7];
  constexpr float CNT = (float)(O * 128);
  const float mean = tot / CNT;
  float var = (tot2 - tot*mean) / (CNT - 1.f);   // unbiased, ddof=1
  var = fmaxf(var, 0.f);
  const float inv = 1.f / (sqrtf(var) + 1e-5f);
  *out_mean = mean; *out_inv = inv;

  // store phase (may alias the dead input region)
  if constexpr (!IS_L3){
#pragma unroll
    for (int n = 0; n < NTL; ++n){
      const int m = (nt0 + n)*32 + l31;
      const bool valid = (m <= 126);
#pragma unroll
      for (int p = 0; p < PAIR; ++p){
#pragma unroll
        for (int g = 0; g < 4; ++g){
          const int rowb = r0 + p*32 + 8*g + 4*h;
          float f[4];
#pragma unroll
          for (int q = 0; q < 4; ++q){
            float v = (acc[n][p][4*g + q] - mean) * inv;
            if constexpr (LEAKY) v = lk(v);
            f[q] = v;
          }
          union { ushort4v v; unsigned int d[2]; } pk;
          pk.d[0] = cvtpk_bf16(f[0], f[1]);
          pk.d[1] = cvtpk_bf16(f[2], f[3]);
          if (valid) *(ushort4v*)(bOut + (size_t)(m+1)*OST + rowb) = pk.v;
        }
      }
    }
    // node-0 row: normalized zero
    if (tid < O/8){
      float f0 = (0.f - mean) * inv;
      if constexpr (LEAKY) f0 = lk(f0);
      const u16 v0 = f2bf(f0);
      ushort8v z;
#pragma unroll
      for (int e = 0; e < 8; ++e) z[e] = v0;
      *(ushort8v*)(bOut + tid*8) = z;
    }
  } else {
    // raw fp32 (stride OST floats, odd -> conflict-free); maxpool applies
    // (max(raw)-mean)*inv via monotonicity. Node-0 raw == 0 handled by caller.
#pragma unroll
    for (int n = 0; n < NTL; ++n){
      const int m = (nt0 + n)*32 + l31;
      if (m <= 126){
#pragma unroll
        for (int p = 0; p < PAIR; ++p)
#pragma unroll
          for (int g = 0; g < 4; ++g){
            const int rowb = r0 + p*32 + 8*g + 4*h;
#pragma unroll
            for (int q = 0; q < 4; ++q)
              bOutF[(size_t)(m+1)*OST + rowb + q] = acc[n][p][4*g + q];
          }
      }
    }
  }
  __syncthreads();
}

// LDS: one 66 KB union buffer, reused by every stage:
//   trees in  [128 n][136] bf16   34816 B
//   L1 out    [128 n][264] bf16   67584 B  (over dead trees)
//   L2 out    [128 n][136] bf16   34816 B  (over dead L1)
//   L3 raw    [128 n][67]  fp32   34304 B  (over dead L2)
// 256 threads / 4 waves, 2 blocks/CU (phase-offset overlap between the two
// resident blocks measured better than 1x512-thr or 1-blk 2-tree variants).
__global__ __launch_bounds__(256, 2) void bao_main(
    const float* __restrict__ trees, const int* __restrict__ gidx,
    const u16* __restrict__ wsW,
    const float* __restrict__ b1, const float* __restrict__ b2, const float* __restrict__ b3,
    const float* __restrict__ W4, const float* __restrict__ b4,
    const float* __restrict__ W5, const float* __restrict__ b5,
    float* __restrict__ dout)
{
  __shared__ __align__(16) u16 buf[33792];      // 67584 B union buffer
  __shared__ int   sidx[384];
  __shared__ float sstat[8];
  __shared__ float spoolP[256];
  __shared__ float spool[64];
  __shared__ float sh[32];

  const int tid = threadIdx.x;
  const int b = blockIdx.x;
  float* bufF = (float*)buf;

  // load + transpose + quantize trees[b] (fp32 [128 c][128 n] -> bf16 buf[n][c]).
  // Packed ds_write_b128; HW cvt_pk for the f32->bf16 pack.
  const float* tb = trees + (size_t)b * (128*128);
  {
    const int ngrp = tid & 31, cg = tid >> 5;
#pragma unroll
    for (int it = 0; it < 8; ++it){
      const int n  = ngrp + 32*(it & 3);
      const int c0 = (cg + 8*(it >> 2))*8;
      float fv[8];
#pragma unroll
      for (int cc = 0; cc < 8; ++cc) fv[cc] = tb[(c0 + cc)*128 + n];
      union { ushort8v v; unsigned int d[4]; } pk;
#pragma unroll
      for (int p = 0; p < 4; ++p) pk.d[p] = cvtpk_bf16(fv[2*p], fv[2*p+1]);
      *(ushort8v*)(buf + n*136 + c0) = pk.v;
    }
  }
  // idx (381 entries, pad to 384 with 0)
  if (tid < 96){
#pragma unroll
    for (int k = 0; k < 4; ++k){
      int ii = tid*4 + k;
      sidx[ii] = (ii < 381) ? gidx[(size_t)b*381 + ii] : 0;
    }
  }
  __syncthreads();

  float mean, inv;
  //            CIN  O   SIN OST NTL PAIR LEAKY IS_L3
  do_layer<128,256,136,264, 2, 4, true ,false>(wsW,          b1, buf, buf, nullptr, sidx, sstat, tid, &mean, &inv);
  do_layer<256,128,264,136, 1, 4, true ,false>(wsW + 98304,  b2, buf, buf, nullptr, sidx, sstat, tid, &mean, &inv);
  do_layer<128, 64,136, 67, 1, 2, false,true >(wsW + 196608, b3, buf, nullptr, bufF, sidx, sstat, tid, &mean, &inv);

  // max-pool over nodes (raw fp32, stride 67); node-0 raw is exactly 0 so the
  // 0.f floor is exact. max(normalized) = (max(raw) - mean)*inv (monotone).
  {
    const int ch = tid & 63, seg = tid >> 6;
    float mx = 0.f;
    const int nd0 = seg*32 + (seg == 0 ? 1 : 0);
    for (int nd = nd0; nd < seg*32 + 32; ++nd) mx = fmaxf(mx, bufF[nd*67 + ch]);
    spoolP[seg*64 + ch] = mx;
  }
  __syncthreads();
  if (tid < 64){
    float mx = fmaxf(fmaxf(spoolP[tid], spoolP[64 + tid]),
                     fmaxf(spoolP[128 + tid], spoolP[192 + tid]));
    spool[tid] = (mx - mean) * inv;
  }
  __syncthreads();
  if (tid < 32){
    float a = b4[tid];
    for (int c = 0; c < 64; ++c) a += spool[c] * W4[tid*64 + c];
    sh[tid] = lk(a);
  }
  __syncthreads();
  if (tid == 0){
    float o = b5[0];
    for (int i = 0; i < 32; ++i) o += sh[i] * W5[i];
    dout[b] = o;
  }
}

extern "C" void kernel_launch(void* const* d_in, const int* in_sizes, int n_in,
                              void* d_out, int out_size, void* d_ws, size_t ws_size,
                              hipStream_t stream) {
  const float* trees = (const float*)d_in[0];
  const int*   gidx  = (const int*)d_in[1];
  const float* W1 = (const float*)d_in[2];
  const float* b1 = (const float*)d_in[3];
  const float* W2 = (const float*)d_in[4];
  const float* b2 = (const float*)d_in[5];
  const float* W3 = (const float*)d_in[6];
  const float* b3 = (const float*)d_in[7];
  const float* W4 = (const float*)d_in[8];
  const float* b4 = (const float*)d_in[9];
  const float* W5 = (const float*)d_in[10];
  const float* b5 = (const float*)d_in[11];
  u16* wsW = (u16*)d_ws;   // 221184 bf16 elems = 432 KB of tiled+quantized weights

  permute_w<<<864, 256, 0, stream>>>(W1, W2, W3, wsW);
  bao_main<<<2048, 256, 0, stream>>>(trees, gidx, wsW, b1, b2, b3, W4, b4, W5, b5,
                                     (float*)d_out);
}

// Round 7
// 369.529 us; speedup vs baseline: 1.0127x; 1.0127x over previous
//
#include <hip/hip_runtime.h>

typedef unsigned short u16;
typedef __attribute__((ext_vector_type(8)))  short          short8;
typedef __attribute__((ext_vector_type(8)))  unsigned short ushort8v;
typedef __attribute__((ext_vector_type(4)))  unsigned short ushort4v;
typedef __attribute__((ext_vector_type(16))) float          float16v;

__device__ __forceinline__ float bf2f(u16 u){
  union { unsigned int i; float f; } x; x.i = ((unsigned int)u) << 16; return x.f;
}
// scalar fallback (node-0 broadcast only) — RNE, identical to v_cvt_pk_bf16_f32
__device__ __forceinline__ u16 f2bf(float f){
  union { float f; unsigned int i; } x; x.f = f;
  unsigned int u = x.i;
  unsigned int r = (u + 0x7FFFu + ((u >> 16) & 1u)) >> 16;
  return (u16)r;
}
// HW packed f32x2 -> bf16x2 (RNE), 1 VALU op for 2 elements.
__device__ __forceinline__ unsigned int cvtpk_bf16(float lo, float hi){
  unsigned int r;
  asm("v_cvt_pk_bf16_f32 %0, %1, %2" : "=v"(r) : "v"(lo), "v"(hi));
  return r;
}
// leaky-relu, branchless
__device__ __forceinline__ float lk(float v){ return fmaxf(v, 0.01f*v); }

// ------- weight permute+quantize into MFMA-fragment-TILED layout -------------
// Tile = (32 out-rows) x (one k-step of 16): 512 bf16 = 1 KB, stored as
// lane-major fragments: elem[(tile*64 + lane)*8 + e], where lane l holds
// A[row = rb*32 + (l&31)][k = jk*16 + (l>>5)*8 + e].  A-loads in the k-loop
// become ONE fully-coalesced 1 KB burst per instruction.
// ws layout (bf16): L1 @0 (8 rb x 24 jk tiles), L2 @98304 (4 x 48), L3 @196608 (2 x 24)
// Single copy (432 KB, L2-resident). FAILED probes: 8x replication (capacity),
// k-phase rotation (spill), 512-thr occupancy (null), 2-tree A-share (lost
// overlap), PAIR=4 in L1 (spill: L1 k-loop is the 128-acc register peak).
__global__ void permute_w(const float* __restrict__ W1, const float* __restrict__ W2,
                          const float* __restrict__ W3, u16* __restrict__ ws){
  int t = blockIdx.x*256 + threadIdx.x;
  const float* src; u16* dst; int C, local;
  if (t < 98304)       { src = W1; dst = ws;          C = 128; local = t; }
  else if (t < 196608) { src = W2; dst = ws + 98304;  C = 256; local = t - 98304; }
  else if (t < 221184) { src = W3; dst = ws + 196608; C = 128; local = t - 196608; }
  else return;
  const int NJK  = 3*C/16;
  const int tile = local >> 9, within = local & 511;
  const int lane = within >> 3, e = within & 7;
  const int rb = tile / NJK, jk = tile - rb*NJK;
  const int o  = rb*32 + (lane & 31);
  const int kg = jk*16 + (lane >> 5)*8 + e;
  const int j  = kg / C, c = kg - j*C;
  dst[local] = f2bf(src[o*3*C + c*3 + j]);
}

// ---------------- fused per-tree layer (4 waves, in-register output) ----------
// GEMM out[O x 127] = W[O x 3C] * G, where G[j*C+c][m] = bIn[idx[3m+j]][c]
// PAIR = A-tiles (32 rows each) per wave; each random-node B-gather feeds
// PAIR MFMAs. PAIR=4 ONLY in L2: its k-loop holds just 64 acc regs, so the
// extra A[4] (16 VGPRs) fits under L1's 124-reg peak -> no spill, and L2's
// gathers (the largest share, NJK=48) halve. L1 must stay PAIR=2: its 128-acc
// k-loop spills with A[4] (measured: WRITE_SIZE 64KB -> 39.6MB, +45us).
// Wave w: u0 = w*NTL; rbg = u0>>2 (PAIR-group), nt0 = u0&3.
// Output stays in acc until after the stats __syncthreads (fences k-loop LDS
// reads), THEN is written to bOut/bOutF — which may ALIAS bIn.
template<int CIN, int O, int SIN, int OST, int NTL, int PAIR, bool LEAKY, bool IS_L3>
__device__ __forceinline__ void do_layer(const u16* __restrict__ Wt,
                                         const float* __restrict__ bias,
                                         const u16* bIn, u16* bOut, float* bOutF,
                                         const int* sidx, float* sstat,
                                         int tid, float* out_mean, float* out_inv)
{
  constexpr int KS  = CIN/16;     // k-steps per j segment
  constexpr int NJK = 3*KS;       // total k-steps
  static_assert((O/(32*PAIR))*4 == 4*NTL, "work split mismatch");
  const int w = tid >> 6, lane = tid & 63, l31 = lane & 31, h = lane >> 5;

  const int u0  = w*NTL;
  const int rbg = u0 >> 2;        // PAIR-tile row-group id
  const int nt0 = u0 & 3;         // first n-tile
  const int r0  = rbg * 32 * PAIR;

  // tiled A bases: tile index = (rbg*PAIR + p)*NJK + jk, lane-major inside
  const u16* aP[PAIR];
#pragma unroll
  for (int p = 0; p < PAIR; ++p)
    aP[p] = Wt + ((size_t)(rbg*PAIR + p)*NJK)*512 + lane*8;

  int boff[NTL][3];
#pragma unroll
  for (int n = 0; n < NTL; ++n){
    int m = (nt0 + n)*32 + l31;   // position 0..127 (127 is pad, masked below)
#pragma unroll
    for (int j = 0; j < 3; ++j){
      int i = sidx[3*m + j];      // m==127 hits zero-padded sidx[381..383]
      boff[n][j] = i*SIN + h*8;
    }
  }

  float16v acc[NTL][PAIR];
#pragma unroll
  for (int n = 0; n < NTL; ++n)
#pragma unroll
    for (int p = 0; p < PAIR; ++p) acc[n][p] = {};

#pragma unroll
  for (int jk = 0; jk < NJK; ++jk){
    const int j    = jk / KS;
    const int coff = (jk - j*KS)*16;
    short8 A[PAIR];
#pragma unroll
    for (int p = 0; p < PAIR; ++p) A[p] = *(const short8*)(aP[p] + jk*512);
#pragma unroll
    for (int n = 0; n < NTL; ++n){
      short8 Bf = *(const short8*)(bIn + boff[n][j] + coff);
#pragma unroll
      for (int p = 0; p < PAIR; ++p)
        acc[n][p] = __builtin_amdgcn_mfma_f32_32x32x16_bf16(A[p], Bf, acc[n][p], 0, 0, 0);
    }
  }

  // post-loop: bias add (L2-hot, off the k-loop critical path) + stats partials
  float s = 0.f, s2 = 0.f;
#pragma unroll
  for (int n = 0; n < NTL; ++n){
    const int m = (nt0 + n)*32 + l31;
    const bool valid = (m <= 126);
#pragma unroll
    for (int p = 0; p < PAIR; ++p)
#pragma unroll
      for (int g = 0; g < 4; ++g){
        const int rowb = r0 + p*32 + 8*g + 4*h;   // C/D row = (reg&3)+8*(reg>>2)+4h
#pragma unroll
        for (int q = 0; q < 4; ++q){
          float raw = acc[n][p][4*g + q] + bias[rowb + q];
          acc[n][p][4*g + q] = raw;
          if (valid){ s += raw; s2 += raw*raw; }
        }
      }
  }

  // block-wide stats; this __syncthreads also FENCES all k-loop reads of bIn,
  // making it safe for the store phase below to overwrite bIn's region.
#pragma unroll
  for (int off = 32; off >= 1; off >>= 1){
    s  += __shfl_down(s,  off, 64);
    s2 += __shfl_down(s2, off, 64);
  }
  if (lane == 0){ sstat[w*2] = s; sstat[w*2+1] = s2; }
  __syncthreads();

  const float tot  = sstat[0] + sstat[2] + sstat[4] + sstat[6];
  const float tot2 = sstat[1] + sstat[3] + sstat[5] + sstat[7];
  constexpr float CNT = (float)(O * 128);
  const float mean = tot / CNT;
  float var = (tot2 - tot*mean) / (CNT - 1.f);   // unbiased, ddof=1
  var = fmaxf(var, 0.f);
  const float inv = 1.f / (sqrtf(var) + 1e-5f);
  *out_mean = mean; *out_inv = inv;

  // store phase (may alias the dead input region)
  if constexpr (!IS_L3){
#pragma unroll
    for (int n = 0; n < NTL; ++n){
      const int m = (nt0 + n)*32 + l31;
      const bool valid = (m <= 126);
#pragma unroll
      for (int p = 0; p < PAIR; ++p){
#pragma unroll
        for (int g = 0; g < 4; ++g){
          const int rowb = r0 + p*32 + 8*g + 4*h;
          float f[4];
#pragma unroll
          for (int q = 0; q < 4; ++q){
            float v = (acc[n][p][4*g + q] - mean) * inv;
            if constexpr (LEAKY) v = lk(v);
            f[q] = v;
          }
          union { ushort4v v; unsigned int d[2]; } pk;
          pk.d[0] = cvtpk_bf16(f[0], f[1]);
          pk.d[1] = cvtpk_bf16(f[2], f[3]);
          if (valid) *(ushort4v*)(bOut + (size_t)(m+1)*OST + rowb) = pk.v;
        }
      }
    }
    // node-0 row: normalized zero
    if (tid < O/8){
      float f0 = (0.f - mean) * inv;
      if constexpr (LEAKY) f0 = lk(f0);
      const u16 v0 = f2bf(f0);
      ushort8v z;
#pragma unroll
      for (int e = 0; e < 8; ++e) z[e] = v0;
      *(ushort8v*)(bOut + tid*8) = z;
    }
  } else {
    // raw fp32 (stride OST floats, odd -> conflict-free); maxpool applies
    // (max(raw)-mean)*inv via monotonicity. Node-0 raw == 0 handled by caller.
#pragma unroll
    for (int n = 0; n < NTL; ++n){
      const int m = (nt0 + n)*32 + l31;
      if (m <= 126){
#pragma unroll
        for (int p = 0; p < PAIR; ++p)
#pragma unroll
          for (int g = 0; g < 4; ++g){
            const int rowb = r0 + p*32 + 8*g + 4*h;
#pragma unroll
            for (int q = 0; q < 4; ++q)
              bOutF[(size_t)(m+1)*OST + rowb + q] = acc[n][p][4*g + q];
          }
      }
    }
  }
  __syncthreads();
}

// LDS: one 66 KB union buffer, reused by every stage:
//   trees in  [128 n][136] bf16   34816 B
//   L1 out    [128 n][264] bf16   67584 B  (over dead trees)
//   L2 out    [128 n][136] bf16   34816 B  (over dead L1)
//   L3 raw    [128 n][67]  fp32   34304 B  (over dead L2)
// 256 threads / 4 waves, 2 blocks/CU (phase-offset overlap between the two
// resident blocks measured better than 1x512-thr or 1-blk 2-tree variants).
__global__ __launch_bounds__(256, 2) void bao_main(
    const float* __restrict__ trees, const int* __restrict__ gidx,
    const u16* __restrict__ wsW,
    const float* __restrict__ b1, const float* __restrict__ b2, const float* __restrict__ b3,
    const float* __restrict__ W4, const float* __restrict__ b4,
    const float* __restrict__ W5, const float* __restrict__ b5,
    float* __restrict__ dout)
{
  __shared__ __align__(16) u16 buf[33792];      // 67584 B union buffer
  __shared__ int   sidx[384];
  __shared__ float sstat[8];
  __shared__ float spoolP[256];
  __shared__ float spool[64];
  __shared__ float sh[32];

  const int tid = threadIdx.x;
  const int b = blockIdx.x;
  float* bufF = (float*)buf;

  // load + transpose + quantize trees[b] (fp32 [128 c][128 n] -> bf16 buf[n][c]).
  // Packed ds_write_b128; HW cvt_pk for the f32->bf16 pack.
  const float* tb = trees + (size_t)b * (128*128);
  {
    const int ngrp = tid & 31, cg = tid >> 5;
#pragma unroll
    for (int it = 0; it < 8; ++it){
      const int n  = ngrp + 32*(it & 3);
      const int c0 = (cg + 8*(it >> 2))*8;
      float fv[8];
#pragma unroll
      for (int cc = 0; cc < 8; ++cc) fv[cc] = tb[(c0 + cc)*128 + n];
      union { ushort8v v; unsigned int d[4]; } pk;
#pragma unroll
      for (int p = 0; p < 4; ++p) pk.d[p] = cvtpk_bf16(fv[2*p], fv[2*p+1]);
      *(ushort8v*)(buf + n*136 + c0) = pk.v;
    }
  }
  // idx (381 entries, pad to 384 with 0)
  if (tid < 96){
#pragma unroll
    for (int k = 0; k < 4; ++k){
      int ii = tid*4 + k;
      sidx[ii] = (ii < 381) ? gidx[(size_t)b*381 + ii] : 0;
    }
  }
  __syncthreads();

  float mean, inv;
  //            CIN  O   SIN OST NTL PAIR LEAKY IS_L3
  do_layer<128,256,136,264, 4, 2, true ,false>(wsW,          b1, buf, buf, nullptr, sidx, sstat, tid, &mean, &inv);
  do_layer<256,128,264,136, 1, 4, true ,false>(wsW + 98304,  b2, buf, buf, nullptr, sidx, sstat, tid, &mean, &inv);
  do_layer<128, 64,136, 67, 1, 2, false,true >(wsW + 196608, b3, buf, nullptr, bufF, sidx, sstat, tid, &mean, &inv);

  // max-pool over nodes (raw fp32, stride 67); node-0 raw is exactly 0 so the
  // 0.f floor is exact. max(normalized) = (max(raw) - mean)*inv (monotone).
  {
    const int ch = tid & 63, seg = tid >> 6;
    float mx = 0.f;
    const int nd0 = seg*32 + (seg == 0 ? 1 : 0);
    for (int nd = nd0; nd < seg*32 + 32; ++nd) mx = fmaxf(mx, bufF[nd*67 + ch]);
    spoolP[seg*64 + ch] = mx;
  }
  __syncthreads();
  if (tid < 64){
    float mx = fmaxf(fmaxf(spoolP[tid], spoolP[64 + tid]),
                     fmaxf(spoolP[128 + tid], spoolP[192 + tid]));
    spool[tid] = (mx - mean) * inv;
  }
  __syncthreads();
  if (tid < 32){
    float a = b4[tid];
    for (int c = 0; c < 64; ++c) a += spool[c] * W4[tid*64 + c];
    sh[tid] = lk(a);
  }
  __syncthreads();
  if (tid == 0){
    float o = b5[0];
    for (int i = 0; i < 32; ++i) o += sh[i] * W5[i];
    dout[b] = o;
  }
}

extern "C" void kernel_launch(void* const* d_in, const int* in_sizes, int n_in,
                              void* d_out, int out_size, void* d_ws, size_t ws_size,
                              hipStream_t stream) {
  const float* trees = (const float*)d_in[0];
  const int*   gidx  = (const int*)d_in[1];
  const float* W1 = (const float*)d_in[2];
  const float* b1 = (const float*)d_in[3];
  const float* W2 = (const float*)d_in[4];
  const float* b2 = (const float*)d_in[5];
  const float* W3 = (const float*)d_in[6];
  const float* b3 = (const float*)d_in[7];
  const float* W4 = (const float*)d_in[8];
  const float* b4 = (const float*)d_in[9];
  const float* W5 = (const float*)d_in[10];
  const float* b5 = (const float*)d_in[11];
  u16* wsW = (u16*)d_ws;   // 221184 bf16 elems = 432 KB of tiled+quantized weights

  permute_w<<<864, 256, 0, stream>>>(W1, W2, W3, wsW);
  bao_main<<<2048, 256, 0, stream>>>(trees, gidx, wsW, b1, b2, b3, W4, b4, W5, b5,
                                     (float*)d_out);
}

// Round 8
// 335.448 us; speedup vs baseline: 1.1156x; 1.1016x over previous
//
#include <hip/hip_runtime.h>

typedef unsigned short u16;
typedef __attribute__((ext_vector_type(8)))  short          short8;
typedef __attribute__((ext_vector_type(4)))  short          short4v;
typedef __attribute__((ext_vector_type(8)))  unsigned short ushort8v;
typedef __attribute__((ext_vector_type(4)))  unsigned short ushort4v;
typedef __attribute__((ext_vector_type(16))) float          float16v;

__device__ __forceinline__ float bf2f(u16 u){
  union { unsigned int i; float f; } x; x.i = ((unsigned int)u) << 16; return x.f;
}
// scalar fallback (node-0 broadcast only) — RNE, identical to v_cvt_pk_bf16_f32
__device__ __forceinline__ u16 f2bf(float f){
  union { float f; unsigned int i; } x; x.f = f;
  unsigned int u = x.i;
  unsigned int r = (u + 0x7FFFu + ((u >> 16) & 1u)) >> 16;
  return (u16)r;
}
// HW packed f32x2 -> bf16x2 (RNE), 1 VALU op for 2 elements.
__device__ __forceinline__ unsigned int cvtpk_bf16(float lo, float hi){
  unsigned int r;
  asm("v_cvt_pk_bf16_f32 %0, %1, %2" : "=v"(r) : "v"(lo), "v"(hi));
  return r;
}
// leaky-relu, branchless
__device__ __forceinline__ float lk(float v){ return fmaxf(v, 0.01f*v); }

// ------- weight permute+quantize into MFMA-fragment-TILED layout -------------
// Tile = (32 out-rows) x (one k-step of 16): 512 bf16 = 1 KB, stored as
// lane-major fragments: elem[(tile*64 + lane)*8 + e], where lane l holds
// A[row = rb*32 + (l&31)][k = jk*16 + (l>>5)*8 + e].  A-loads in the k-loop
// become ONE fully-coalesced 1 KB burst per instruction.
// ws layout (bf16): L1 @0 (8 rb x 24 jk tiles), L2 @98304 (4 x 48), L3 @196608 (2 x 24)
// Single copy (432 KB, L2-resident). FAILED probes: 8x replication (capacity),
// k-phase rotation (spill), 512-thr occupancy (null), 2-tree A-share (lost
// overlap), PAIR=4 in L1 (spill), PAIR=4 in L2 (doubled A-path traffic,
// +35us -- the A stream is the latency-critical resource, never add to it).
__global__ void permute_w(const float* __restrict__ W1, const float* __restrict__ W2,
                          const float* __restrict__ W3, u16* __restrict__ ws){
  int t = blockIdx.x*256 + threadIdx.x;
  const float* src; u16* dst; int C, local;
  if (t < 98304)       { src = W1; dst = ws;          C = 128; local = t; }
  else if (t < 196608) { src = W2; dst = ws + 98304;  C = 256; local = t - 98304; }
  else if (t < 221184) { src = W3; dst = ws + 196608; C = 128; local = t - 196608; }
  else return;
  const int NJK  = 3*C/16;
  const int tile = local >> 9, within = local & 511;
  const int lane = within >> 3, e = within & 7;
  const int rb = tile / NJK, jk = tile - rb*NJK;
  const int o  = rb*32 + (lane & 31);
  const int kg = jk*16 + (lane >> 5)*8 + e;
  const int j  = kg / C, c = kg - j*C;
  dst[local] = f2bf(src[o*3*C + c*3 + j]);
}

// ---------------- fused per-tree layer (4 waves, in-register output) ----------
// GEMM out[O x 127] = W[O x 3C] * G, where G[j*C+c][m] = bIn[idx[3m+j]][c]
// B-GATHER BANKING: a 16B ds_read_b128 at a random row with 16B-aligned
// stride puts every lane's 4-dword window at slot ≡0 mod 4 -> only 8 slots
// for 32 lanes -> deterministic ~4-way conflict (measured +8cyc/gather).
// Fix: stride ≡ 2 mod 4 dwords (SIN=140/268 elems -> 70/134 dwords) and
// gather as 2x ds_read_b64 (2-dword granular, 16 slots, ~2-way = free).
// Output stays in acc until after the stats __syncthreads (fences k-loop LDS
// reads), THEN is written to bOut/bOutF — which may ALIAS bIn.
template<int CIN, int O, int SIN, int OST, int NTL, int PAIR, bool LEAKY, bool IS_L3>
__device__ __forceinline__ void do_layer(const u16* __restrict__ Wt,
                                         const float* __restrict__ bias,
                                         const u16* bIn, u16* bOut, float* bOutF,
                                         const int* sidx, float* sstat,
                                         int tid, float* out_mean, float* out_inv)
{
  constexpr int KS  = CIN/16;     // k-steps per j segment
  constexpr int NJK = 3*KS;       // total k-steps
  static_assert((O/(32*PAIR))*4 == 4*NTL, "work split mismatch");
  const int w = tid >> 6, lane = tid & 63, l31 = lane & 31, h = lane >> 5;

  const int u0  = w*NTL;
  const int rbg = u0 >> 2;        // PAIR-tile row-group id
  const int nt0 = u0 & 3;         // first n-tile
  const int r0  = rbg * 32 * PAIR;

  // tiled A bases: tile index = (rbg*PAIR + p)*NJK + jk, lane-major inside
  const u16* aP[PAIR];
#pragma unroll
  for (int p = 0; p < PAIR; ++p)
    aP[p] = Wt + ((size_t)(rbg*PAIR + p)*NJK)*512 + lane*8;

  int boff[NTL][3];
#pragma unroll
  for (int n = 0; n < NTL; ++n){
    int m = (nt0 + n)*32 + l31;   // position 0..127 (127 is pad, masked below)
#pragma unroll
    for (int j = 0; j < 3; ++j){
      int i = sidx[3*m + j];      // m==127 hits zero-padded sidx[381..383]
      boff[n][j] = i*SIN + h*8;
    }
  }

  float16v acc[NTL][PAIR];
#pragma unroll
  for (int n = 0; n < NTL; ++n)
#pragma unroll
    for (int p = 0; p < PAIR; ++p) acc[n][p] = {};

#pragma unroll
  for (int jk = 0; jk < NJK; ++jk){
    const int j    = jk / KS;
    const int coff = (jk - j*KS)*16;
    short8 A[PAIR];
#pragma unroll
    for (int p = 0; p < PAIR; ++p) A[p] = *(const short8*)(aP[p] + jk*512);
#pragma unroll
    for (int n = 0; n < NTL; ++n){
      const u16* bp = bIn + boff[n][j] + coff;
      union { short8 v; short4v hh[2]; } Bf;
      Bf.hh[0] = *(const short4v*)(bp);        // ds_read_b64 (8B-aligned)
      Bf.hh[1] = *(const short4v*)(bp + 4);    // ds_read_b64
#pragma unroll
      for (int p = 0; p < PAIR; ++p)
        acc[n][p] = __builtin_amdgcn_mfma_f32_32x32x16_bf16(A[p], Bf.v, acc[n][p], 0, 0, 0);
    }
  }

  // post-loop: bias add (L2-hot, off the k-loop critical path) + stats partials
  float s = 0.f, s2 = 0.f;
#pragma unroll
  for (int n = 0; n < NTL; ++n){
    const int m = (nt0 + n)*32 + l31;
    const bool valid = (m <= 126);
#pragma unroll
    for (int p = 0; p < PAIR; ++p)
#pragma unroll
      for (int g = 0; g < 4; ++g){
        const int rowb = r0 + p*32 + 8*g + 4*h;   // C/D row = (reg&3)+8*(reg>>2)+4h
#pragma unroll
        for (int q = 0; q < 4; ++q){
          float raw = acc[n][p][4*g + q] + bias[rowb + q];
          acc[n][p][4*g + q] = raw;
          if (valid){ s += raw; s2 += raw*raw; }
        }
      }
  }

  // block-wide stats; this __syncthreads also FENCES all k-loop reads of bIn,
  // making it safe for the store phase below to overwrite bIn's region.
#pragma unroll
  for (int off = 32; off >= 1; off >>= 1){
    s  += __shfl_down(s,  off, 64);
    s2 += __shfl_down(s2, off, 64);
  }
  if (lane == 0){ sstat[w*2] = s; sstat[w*2+1] = s2; }
  __syncthreads();

  const float tot  = sstat[0] + sstat[2] + sstat[4] + sstat[6];
  const float tot2 = sstat[1] + sstat[3] + sstat[5] + sstat[7];
  constexpr float CNT = (float)(O * 128);
  const float mean = tot / CNT;
  float var = (tot2 - tot*mean) / (CNT - 1.f);   // unbiased, ddof=1
  var = fmaxf(var, 0.f);
  const float inv = 1.f / (sqrtf(var) + 1e-5f);
  *out_mean = mean; *out_inv = inv;

  // store phase (may alias the dead input region)
  if constexpr (!IS_L3){
#pragma unroll
    for (int n = 0; n < NTL; ++n){
      const int m = (nt0 + n)*32 + l31;
      const bool valid = (m <= 126);
#pragma unroll
      for (int p = 0; p < PAIR; ++p){
#pragma unroll
        for (int g = 0; g < 4; ++g){
          const int rowb = r0 + p*32 + 8*g + 4*h;
          float f[4];
#pragma unroll
          for (int q = 0; q < 4; ++q){
            float v = (acc[n][p][4*g + q] - mean) * inv;
            if constexpr (LEAKY) v = lk(v);
            f[q] = v;
          }
          union { ushort4v v; unsigned int d[2]; } pk;
          pk.d[0] = cvtpk_bf16(f[0], f[1]);
          pk.d[1] = cvtpk_bf16(f[2], f[3]);
          if (valid) *(ushort4v*)(bOut + (size_t)(m+1)*OST + rowb) = pk.v;
        }
      }
    }
    // node-0 row: normalized zero
    if (tid < O/8){
      float f0 = (0.f - mean) * inv;
      if constexpr (LEAKY) f0 = lk(f0);
      const u16 v0 = f2bf(f0);
      ushort8v z;
#pragma unroll
      for (int e = 0; e < 8; ++e) z[e] = v0;
      *(ushort8v*)(bOut + tid*8) = z;
    }
  } else {
    // raw fp32 (stride OST floats, odd -> conflict-free); maxpool applies
    // (max(raw)-mean)*inv via monotonicity. Node-0 raw == 0 handled by caller.
#pragma unroll
    for (int n = 0; n < NTL; ++n){
      const int m = (nt0 + n)*32 + l31;
      if (m <= 126){
#pragma unroll
        for (int p = 0; p < PAIR; ++p)
#pragma unroll
          for (int g = 0; g < 4; ++g){
            const int rowb = r0 + p*32 + 8*g + 4*h;
#pragma unroll
            for (int q = 0; q < 4; ++q)
              bOutF[(size_t)(m+1)*OST + rowb + q] = acc[n][p][4*g + q];
          }
      }
    }
  }
  __syncthreads();
}

// LDS: one 67 KB union buffer, reused by every stage (strides chosen ≡ 2 mod
// 4 dwords for conflict-free b64 gathers):
//   trees in  [128 n][140] bf16   35840 B
//   L1 out    [128 n][268] bf16   68608 B  (over dead trees)
//   L2 out    [128 n][140] bf16   35840 B  (over dead L1)
//   L3 raw    [128 n][67]  fp32   34304 B  (over dead L2)
// 256 threads / 4 waves, 2 blocks/CU (phase-offset overlap between the two
// resident blocks measured better than 1x512-thr or 1-blk 2-tree variants).
__global__ __launch_bounds__(256, 2) void bao_main(
    const float* __restrict__ trees, const int* __restrict__ gidx,
    const u16* __restrict__ wsW,
    const float* __restrict__ b1, const float* __restrict__ b2, const float* __restrict__ b3,
    const float* __restrict__ W4, const float* __restrict__ b4,
    const float* __restrict__ W5, const float* __restrict__ b5,
    float* __restrict__ dout)
{
  __shared__ __align__(16) u16 buf[34304];      // 68608 B union buffer
  __shared__ int   sidx[384];
  __shared__ float sstat[8];
  __shared__ float spoolP[256];
  __shared__ float spool[64];
  __shared__ float sh[32];

  const int tid = threadIdx.x;
  const int b = blockIdx.x;
  float* bufF = (float*)buf;

  // load + transpose + quantize trees[b] (fp32 [128 c][128 n] -> bf16 buf[n][c]).
  // HW cvt_pk pack; 2x ds_write_b64 (stride 70 dwords -> 2-way = free).
  const float* tb = trees + (size_t)b * (128*128);
  {
    const int ngrp = tid & 31, cg = tid >> 5;
#pragma unroll
    for (int it = 0; it < 8; ++it){
      const int n  = ngrp + 32*(it & 3);
      const int c0 = (cg + 8*(it >> 2))*8;
      float fv[8];
#pragma unroll
      for (int cc = 0; cc < 8; ++cc) fv[cc] = tb[(c0 + cc)*128 + n];
      union { ushort8v v; unsigned int d[4]; ushort4v hh[2]; } pk;
#pragma unroll
      for (int p = 0; p < 4; ++p) pk.d[p] = cvtpk_bf16(fv[2*p], fv[2*p+1]);
      *(ushort4v*)(buf + n*140 + c0)     = pk.hh[0];
      *(ushort4v*)(buf + n*140 + c0 + 4) = pk.hh[1];
    }
  }
  // idx (381 entries, pad to 384 with 0)
  if (tid < 96){
#pragma unroll
    for (int k = 0; k < 4; ++k){
      int ii = tid*4 + k;
      sidx[ii] = (ii < 381) ? gidx[(size_t)b*381 + ii] : 0;
    }
  }
  __syncthreads();

  float mean, inv;
  //            CIN  O   SIN OST NTL PAIR LEAKY IS_L3
  do_layer<128,256,140,268, 4, 2, true ,false>(wsW,          b1, buf, buf, nullptr, sidx, sstat, tid, &mean, &inv);
  do_layer<256,128,268,140, 2, 2, true ,false>(wsW + 98304,  b2, buf, buf, nullptr, sidx, sstat, tid, &mean, &inv);
  do_layer<128, 64,140, 67, 1, 2, false,true >(wsW + 196608, b3, buf, nullptr, bufF, sidx, sstat, tid, &mean, &inv);

  // max-pool over nodes (raw fp32, stride 67); node-0 raw is exactly 0 so the
  // 0.f floor is exact. max(normalized) = (max(raw) - mean)*inv (monotone).
  {
    const int ch = tid & 63, seg = tid >> 6;
    float mx = 0.f;
    const int nd0 = seg*32 + (seg == 0 ? 1 : 0);
    for (int nd = nd0; nd < seg*32 + 32; ++nd) mx = fmaxf(mx, bufF[nd*67 + ch]);
    spoolP[seg*64 + ch] = mx;
  }
  __syncthreads();
  if (tid < 64){
    float mx = fmaxf(fmaxf(spoolP[tid], spoolP[64 + tid]),
                     fmaxf(spoolP[128 + tid], spoolP[192 + tid]));
    spool[tid] = (mx - mean) * inv;
  }
  __syncthreads();
  if (tid < 32){
    float a = b4[tid];
    for (int c = 0; c < 64; ++c) a += spool[c] * W4[tid*64 + c];
    sh[tid] = lk(a);
  }
  __syncthreads();
  if (tid == 0){
    float o = b5[0];
    for (int i = 0; i < 32; ++i) o += sh[i] * W5[i];
    dout[b] = o;
  }
}

extern "C" void kernel_launch(void* const* d_in, const int* in_sizes, int n_in,
                              void* d_out, int out_size, void* d_ws, size_t ws_size,
                              hipStream_t stream) {
  const float* trees = (const float*)d_in[0];
  const int*   gidx  = (const int*)d_in[1];
  const float* W1 = (const float*)d_in[2];
  const float* b1 = (const float*)d_in[3];
  const float* W2 = (const float*)d_in[4];
  const float* b2 = (const float*)d_in[5];
  const float* W3 = (const float*)d_in[6];
  const float* b3 = (const float*)d_in[7];
  const float* W4 = (const float*)d_in[8];
  const float* b4 = (const float*)d_in[9];
  const float* W5 = (const float*)d_in[10];
  const float* b5 = (const float*)d_in[11];
  u16* wsW = (u16*)d_ws;   // 221184 bf16 elems = 432 KB of tiled+quantized weights

  permute_w<<<864, 256, 0, stream>>>(W1, W2, W3, wsW);
  bao_main<<<2048, 256, 0, stream>>>(trees, gidx, wsW, b1, b2, b3, W4, b4, W5, b5,
                                     (float*)d_out);
}

// Round 9
// 325.777 us; speedup vs baseline: 1.1487x; 1.0297x over previous
//
#include <hip/hip_runtime.h>

typedef unsigned short u16;
typedef __attribute__((ext_vector_type(8)))  short          short8;
typedef __attribute__((ext_vector_type(4)))  short          short4v;
typedef __attribute__((ext_vector_type(8)))  unsigned short ushort8v;
typedef __attribute__((ext_vector_type(4)))  unsigned short ushort4v;
typedef __attribute__((ext_vector_type(16))) float          float16v;

__device__ __forceinline__ float bf2f(u16 u){
  union { unsigned int i; float f; } x; x.i = ((unsigned int)u) << 16; return x.f;
}
// scalar fallback (node-0 broadcast only) — RNE, identical to v_cvt_pk_bf16_f32
__device__ __forceinline__ u16 f2bf(float f){
  union { float f; unsigned int i; } x; x.f = f;
  unsigned int u = x.i;
  unsigned int r = (u + 0x7FFFu + ((u >> 16) & 1u)) >> 16;
  return (u16)r;
}
// HW packed f32x2 -> bf16x2 (RNE), 1 VALU op for 2 elements.
__device__ __forceinline__ unsigned int cvtpk_bf16(float lo, float hi){
  unsigned int r;
  asm("v_cvt_pk_bf16_f32 %0, %1, %2" : "=v"(r) : "v"(lo), "v"(hi));
  return r;
}
// leaky-relu, branchless
__device__ __forceinline__ float lk(float v){ return fmaxf(v, 0.01f*v); }

#define WCOPY_ELEMS 221184   // u16 elems per weight copy (L1 98304 + L2 98304 + L3 24576)

// ------- weight permute+quantize into MFMA-fragment-TILED layout -------------
// Tile = (32 out-rows) x (one k-step of 16): 512 bf16 = 1 KB, lane-major
// fragments: elem[(tile*64 + lane)*8 + e], lane l holds
// A[row = rb*32 + (l&31)][k = jk*16 + (l>>5)*8 + e].
// ws layout (bf16): L1 @0 (8 rb x 24 jk tiles), L2 @98304 (4 x 48), L3 @196608 (2 x 24)
// nrep copies (432 KB each): co-XCD blocks alternate copies to break SAME-LINE
// L2 serialization on the lockstep A-stream. 2 copies = 864 KB, still
// L2-comfortable (r2's 8x/3.4MB blew capacity: FETCH +48MB).
__global__ void permute_w(const float* __restrict__ W1, const float* __restrict__ W2,
                          const float* __restrict__ W3, u16* __restrict__ ws, int nrep){
  int t = blockIdx.x*256 + threadIdx.x;
  const float* src; int gb, C, local;
  if (t < 98304)       { src = W1; gb = 0;      C = 128; local = t; }
  else if (t < 196608) { src = W2; gb = 98304;  C = 256; local = t - 98304; }
  else if (t < 221184) { src = W3; gb = 196608; C = 128; local = t - 196608; }
  else return;
  const int NJK  = 3*C/16;
  const int tile = local >> 9, within = local & 511;
  const int lane = within >> 3, e = within & 7;
  const int rb = tile / NJK, jk = tile - rb*NJK;
  const int o  = rb*32 + (lane & 31);
  const int kg = jk*16 + (lane >> 5)*8 + e;
  const int j  = kg / C, c = kg - j*C;
  const u16 v = f2bf(src[o*3*C + c*3 + j]);
  for (int r = 0; r < nrep; ++r)
    ws[(size_t)r*WCOPY_ELEMS + gb + local] = v;
}

// ---------------- fused per-tree layer (4 waves, in-register output) ----------
// GEMM out[O x 127] = W[O x 3C] * G, where G[j*C+c][m] = bIn[idx[3m+j]][c]
// J-SEGMENT ROTATION (jrot): blocks start the k-loop at j-segment jrot, so
// co-resident blocks don't request the SAME weight lines simultaneously
// (same-address L2 requests serialize on one channel -> A-load latency blowup,
// the measured ~75% all-pipe idle). j is WAVE-UNIFORM (scalar); the inner KS
// loop stays fully static -> no runtime register indexing, no spill (r3's
// failure mode). boff[n][j] selected per segment via cndmask ternary.
// Accumulation reassociates across j segments only (~1e-6 fp noise).
// Output stays in acc until after the stats __syncthreads (fences k-loop LDS
// reads), THEN is written to bOut/bOutF — which may ALIAS bIn.
template<int CIN, int O, int SIN, int OST, int NTL, int PAIR, bool LEAKY, bool IS_L3>
__device__ __forceinline__ void do_layer(const u16* __restrict__ Wt,
                                         const float* __restrict__ bias,
                                         const u16* bIn, u16* bOut, float* bOutF,
                                         const int* sidx, float* sstat,
                                         int tid, int jrot,
                                         float* out_mean, float* out_inv)
{
  constexpr int KS  = CIN/16;     // k-steps per j segment
  constexpr int NJK = 3*KS;       // total k-steps
  static_assert((O/(32*PAIR))*4 == 4*NTL, "work split mismatch");
  const int w = tid >> 6, lane = tid & 63, l31 = lane & 31, h = lane >> 5;

  const int u0  = w*NTL;
  const int rbg = u0 >> 2;        // PAIR-tile row-group id
  const int nt0 = u0 & 3;         // first n-tile
  const int r0  = rbg * 32 * PAIR;

  // tiled A bases: tile index = (rbg*PAIR + p)*NJK + jk, lane-major inside
  const u16* aP[PAIR];
#pragma unroll
  for (int p = 0; p < PAIR; ++p)
    aP[p] = Wt + ((size_t)(rbg*PAIR + p)*NJK)*512 + lane*8;

  int boff[NTL][3];
#pragma unroll
  for (int n = 0; n < NTL; ++n){
    int m = (nt0 + n)*32 + l31;   // position 0..127 (127 is pad, masked below)
#pragma unroll
    for (int j = 0; j < 3; ++j){
      int i = sidx[3*m + j];      // m==127 hits zero-padded sidx[381..383]
      boff[n][j] = i*SIN + h*8;
    }
  }

  float16v acc[NTL][PAIR];
#pragma unroll
  for (int n = 0; n < NTL; ++n)
#pragma unroll
    for (int p = 0; p < PAIR; ++p) acc[n][p] = {};

#pragma unroll
  for (int jj = 0; jj < 3; ++jj){
    int j = jj + jrot; if (j >= 3) j -= 3;          // wave-uniform (scalar)
    const u16* aPj[PAIR];
#pragma unroll
    for (int p = 0; p < PAIR; ++p) aPj[p] = aP[p] + (size_t)j*(KS*512);
    int bo[NTL];
#pragma unroll
    for (int n = 0; n < NTL; ++n)
      bo[n] = (j == 0) ? boff[n][0] : ((j == 1) ? boff[n][1] : boff[n][2]);
#pragma unroll
    for (int ks = 0; ks < KS; ++ks){
      const int coff = ks*16;
      short8 A[PAIR];
#pragma unroll
      for (int p = 0; p < PAIR; ++p) A[p] = *(const short8*)(aPj[p] + ks*512);
#pragma unroll
      for (int n = 0; n < NTL; ++n){
        const u16* bp = bIn + bo[n] + coff;
        union { short8 v; short4v hh[2]; } Bf;
        Bf.hh[0] = *(const short4v*)(bp);        // ds_read_b64
        Bf.hh[1] = *(const short4v*)(bp + 4);    // ds_read_b64
#pragma unroll
        for (int p = 0; p < PAIR; ++p)
          acc[n][p] = __builtin_amdgcn_mfma_f32_32x32x16_bf16(A[p], Bf.v, acc[n][p], 0, 0, 0);
      }
    }
  }

  // post-loop: bias add (L2-hot, off the k-loop critical path) + stats partials
  float s = 0.f, s2 = 0.f;
#pragma unroll
  for (int n = 0; n < NTL; ++n){
    const int m = (nt0 + n)*32 + l31;
    const bool valid = (m <= 126);
#pragma unroll
    for (int p = 0; p < PAIR; ++p)
#pragma unroll
      for (int g = 0; g < 4; ++g){
        const int rowb = r0 + p*32 + 8*g + 4*h;   // C/D row = (reg&3)+8*(reg>>2)+4h
#pragma unroll
        for (int q = 0; q < 4; ++q){
          float raw = acc[n][p][4*g + q] + bias[rowb + q];
          acc[n][p][4*g + q] = raw;
          if (valid){ s += raw; s2 += raw*raw; }
        }
      }
  }

  // block-wide stats; this __syncthreads also FENCES all k-loop reads of bIn,
  // making it safe for the store phase below to overwrite bIn's region.
#pragma unroll
  for (int off = 32; off >= 1; off >>= 1){
    s  += __shfl_down(s,  off, 64);
    s2 += __shfl_down(s2, off, 64);
  }
  if (lane == 0){ sstat[w*2] = s; sstat[w*2+1] = s2; }
  __syncthreads();

  const float tot  = sstat[0] + sstat[2] + sstat[4] + sstat[6];
  const float tot2 = sstat[1] + sstat[3] + sstat[5] + sstat[7];
  constexpr float CNT = (float)(O * 128);
  const float mean = tot / CNT;
  float var = (tot2 - tot*mean) / (CNT - 1.f);   // unbiased, ddof=1
  var = fmaxf(var, 0.f);
  const float inv = 1.f / (sqrtf(var) + 1e-5f);
  *out_mean = mean; *out_inv = inv;

  // store phase (may alias the dead input region)
  if constexpr (!IS_L3){
#pragma unroll
    for (int n = 0; n < NTL; ++n){
      const int m = (nt0 + n)*32 + l31;
      const bool valid = (m <= 126);
#pragma unroll
      for (int p = 0; p < PAIR; ++p){
#pragma unroll
        for (int g = 0; g < 4; ++g){
          const int rowb = r0 + p*32 + 8*g + 4*h;
          float f[4];
#pragma unroll
          for (int q = 0; q < 4; ++q){
            float v = (acc[n][p][4*g + q] - mean) * inv;
            if constexpr (LEAKY) v = lk(v);
            f[q] = v;
          }
          union { ushort4v v; unsigned int d[2]; } pk;
          pk.d[0] = cvtpk_bf16(f[0], f[1]);
          pk.d[1] = cvtpk_bf16(f[2], f[3]);
          if (valid) *(ushort4v*)(bOut + (size_t)(m+1)*OST + rowb) = pk.v;
        }
      }
    }
    // node-0 row: normalized zero
    if (tid < O/8){
      float f0 = (0.f - mean) * inv;
      if constexpr (LEAKY) f0 = lk(f0);
      const u16 v0 = f2bf(f0);
      ushort8v z;
#pragma unroll
      for (int e = 0; e < 8; ++e) z[e] = v0;
      *(ushort8v*)(bOut + tid*8) = z;
    }
  } else {
    // raw fp32 (stride OST floats, odd -> conflict-free); maxpool applies
    // (max(raw)-mean)*inv via monotonicity. Node-0 raw == 0 handled by caller.
#pragma unroll
    for (int n = 0; n < NTL; ++n){
      const int m = (nt0 + n)*32 + l31;
      if (m <= 126){
#pragma unroll
        for (int p = 0; p < PAIR; ++p)
#pragma unroll
          for (int g = 0; g < 4; ++g){
            const int rowb = r0 + p*32 + 8*g + 4*h;
#pragma unroll
            for (int q = 0; q < 4; ++q)
              bOutF[(size_t)(m+1)*OST + rowb + q] = acc[n][p][4*g + q];
          }
      }
    }
  }
  __syncthreads();
}

// LDS: one 67 KB union buffer, reused by every stage (strides ≡ 2 mod 4 dwords):
//   trees in  [128 n][140] bf16   35840 B
//   L1 out    [128 n][268] bf16   68608 B  (over dead trees)
//   L2 out    [128 n][140] bf16   35840 B  (over dead L1)
//   L3 raw    [128 n][67]  fp32   34304 B  (over dead L2)
// 256 threads / 4 waves, 2 blocks/CU.
__global__ __launch_bounds__(256, 2) void bao_main(
    const float* __restrict__ trees, const int* __restrict__ gidx,
    const u16* __restrict__ wsAll, int copyMask,
    const float* __restrict__ b1, const float* __restrict__ b2, const float* __restrict__ b3,
    const float* __restrict__ W4, const float* __restrict__ b4,
    const float* __restrict__ W5, const float* __restrict__ b5,
    float* __restrict__ dout)
{
  __shared__ __align__(16) u16 buf[34304];      // 68608 B union buffer
  __shared__ int   sidx[384];
  __shared__ float sstat[8];
  __shared__ float spoolP[256];
  __shared__ float spool[64];
  __shared__ float sh[32];

  const int tid = threadIdx.x;
  const int b = blockIdx.x;
  float* bufF = (float*)buf;

  // decorrelate co-XCD blocks (XCD ~ b%8, co-XCD neighbors step by 8):
  // weight copy from bit 3, j-rotation from bits >=4 -> 6 phase classes.
  const u16* wsW = wsAll + (size_t)((b >> 3) & copyMask) * WCOPY_ELEMS;
  const int jrot = (b >> 4) % 3;

  // load + transpose + quantize trees[b] (fp32 [128 c][128 n] -> bf16 buf[n][c]).
  // HW cvt_pk pack; 2x ds_write_b64 (stride 70 dwords).
  const float* tb = trees + (size_t)b * (128*128);
  {
    const int ngrp = tid & 31, cg = tid >> 5;
#pragma unroll
    for (int it = 0; it < 8; ++it){
      const int n  = ngrp + 32*(it & 3);
      const int c0 = (cg + 8*(it >> 2))*8;
      float fv[8];
#pragma unroll
      for (int cc = 0; cc < 8; ++cc) fv[cc] = tb[(c0 + cc)*128 + n];
      union { ushort8v v; unsigned int d[4]; ushort4v hh[2]; } pk;
#pragma unroll
      for (int p = 0; p < 4; ++p) pk.d[p] = cvtpk_bf16(fv[2*p], fv[2*p+1]);
      *(ushort4v*)(buf + n*140 + c0)     = pk.hh[0];
      *(ushort4v*)(buf + n*140 + c0 + 4) = pk.hh[1];
    }
  }
  // idx (381 entries, pad to 384 with 0)
  if (tid < 96){
#pragma unroll
    for (int k = 0; k < 4; ++k){
      int ii = tid*4 + k;
      sidx[ii] = (ii < 381) ? gidx[(size_t)b*381 + ii] : 0;
    }
  }
  __syncthreads();

  float mean, inv;
  //            CIN  O   SIN OST NTL PAIR LEAKY IS_L3
  do_layer<128,256,140,268, 4, 2, true ,false>(wsW,          b1, buf, buf, nullptr, sidx, sstat, tid, jrot, &mean, &inv);
  do_layer<256,128,268,140, 2, 2, true ,false>(wsW + 98304,  b2, buf, buf, nullptr, sidx, sstat, tid, jrot, &mean, &inv);
  do_layer<128, 64,140, 67, 1, 2, false,true >(wsW + 196608, b3, buf, nullptr, bufF, sidx, sstat, tid, jrot, &mean, &inv);

  // max-pool over nodes (raw fp32, stride 67); node-0 raw is exactly 0 so the
  // 0.f floor is exact. max(normalized) = (max(raw) - mean)*inv (monotone).
  {
    const int ch = tid & 63, seg = tid >> 6;
    float mx = 0.f;
    const int nd0 = seg*32 + (seg == 0 ? 1 : 0);
    for (int nd = nd0; nd < seg*32 + 32; ++nd) mx = fmaxf(mx, bufF[nd*67 + ch]);
    spoolP[seg*64 + ch] = mx;
  }
  __syncthreads();
  if (tid < 64){
    float mx = fmaxf(fmaxf(spoolP[tid], spoolP[64 + tid]),
                     fmaxf(spoolP[128 + tid], spoolP[192 + tid]));
    spool[tid] = (mx - mean) * inv;
  }
  __syncthreads();
  if (tid < 32){
    float a = b4[tid];
    for (int c = 0; c < 64; ++c) a += spool[c] * W4[tid*64 + c];
    sh[tid] = lk(a);
  }
  __syncthreads();
  if (tid == 0){
    float o = b5[0];
    for (int i = 0; i < 32; ++i) o += sh[i] * W5[i];
    dout[b] = o;
  }
}

extern "C" void kernel_launch(void* const* d_in, const int* in_sizes, int n_in,
                              void* d_out, int out_size, void* d_ws, size_t ws_size,
                              hipStream_t stream) {
  const float* trees = (const float*)d_in[0];
  const int*   gidx  = (const int*)d_in[1];
  const float* W1 = (const float*)d_in[2];
  const float* b1 = (const float*)d_in[3];
  const float* W2 = (const float*)d_in[4];
  const float* b2 = (const float*)d_in[5];
  const float* W3 = (const float*)d_in[6];
  const float* b3 = (const float*)d_in[7];
  const float* W4 = (const float*)d_in[8];
  const float* b4 = (const float*)d_in[9];
  const float* W5 = (const float*)d_in[10];
  const float* b5 = (const float*)d_in[11];
  u16* wsW = (u16*)d_ws;

  // 2 weight copies (864 KB) if workspace allows; decorrelates the co-XCD
  // lockstep A-stream without r2's capacity blowout.
  const int nrep = (ws_size >= (size_t)2 * WCOPY_ELEMS * sizeof(u16)) ? 2 : 1;

  permute_w<<<864, 256, 0, stream>>>(W1, W2, W3, wsW, nrep);
  bao_main<<<2048, 256, 0, stream>>>(trees, gidx, wsW, nrep - 1, b1, b2, b3,
                                     W4, b4, W5, b5, (float*)d_out);
}